// Round 1
// baseline (770.915 us; speedup 1.0000x reference)
//
#include <hip/hip_runtime.h>

// Problem constants
constexpr int Qn = 200;
constexpr int Nn = 25;
constexpr int Cn = 640;
constexpr int Hn = 5;
constexpr int Wn = 5;
constexpr int HWn = Hn * Wn;            // 25
constexpr int CHW = Cn * HWn;           // 16000
constexpr float TEMP_INV = 10.0f;       // 1 / 0.1
constexpr float EPSC = 1e-8f;

typedef const float __attribute__((address_space(1)))* gbl_f;
typedef float __attribute__((address_space(3)))* lds_f;

// Stage one 64-channel tile (1600 floats) global -> LDS, 7 async loads.
__device__ __forceinline__ void stage_tile(const float* g, float* b, int lane) {
#pragma unroll
    for (int i = 0; i < 6; ++i)
        __builtin_amdgcn_global_load_lds((gbl_f)(g + i * 256 + lane * 4),
                                         (lds_f)(b + i * 256), 16, 0, 0);
    __builtin_amdgcn_global_load_lds((gbl_f)(g + 1536 + lane),
                                     (lds_f)(b + 1536), 4, 0, 0);
}

// -------------------------------------------------------------------------
// Kernel 1: ONE WAVE per (q,n) tile. 64-thread workgroups, 12.8 KB LDS
// -> 12 waves/CU. Two LDS buffers (fq-tile, fs-tile) with counted
// s_waitcnt vmcnt(7): next tile's 7 loads stay in flight while the current
// tile is consumed — no full vmcnt(0) drain in the steady state, no
// __syncthreads, wave-private butterfly reduction.
//   ms[p] = sum_c fs[c,p] * (sum_p' fq[c,p'])
//   mq[p] = sum_c fq[c,p] * (sum_p' fs[c,p'])
// row-softmax(ms/25) -> s_att ; row-softmax(mq/25)/Q -> atomic into qbar[n].
// -------------------------------------------------------------------------
__global__ __launch_bounds__(64) void attn_kernel(
    const float* __restrict__ fq, const float* __restrict__ fs,
    float* __restrict__ s_att, float* __restrict__ qbar)
{
    __shared__ float bq[1600];   // current fq tile (64 ch x 25)
    __shared__ float bs[1600];   // current fs tile

    const int qn   = blockIdx.x;          // 0 .. Q*N-1
    const int n    = qn % Nn;
    const int lane = threadIdx.x;         // 0..63, one wave

    const float* fq_t = fq + (size_t)qn * CHW;
    const float* fs_t = fs + (size_t)qn * CHW;

    // prologue: tile 0 of both arrays in flight (14 loads outstanding)
    stage_tile(fq_t, bq, lane);
    stage_tile(fs_t, bs, lane);

    float ms[HWn], mq[HWn];
#pragma unroll
    for (int p = 0; p < HWn; ++p) { ms[p] = 0.f; mq[p] = 0.f; }

    for (int t = 0; t < 10; ++t) {
        // --- fq phase: wait for fq_t only (fs_t's 7 loads stay in flight)
        asm volatile("s_waitcnt vmcnt(7)" ::: "memory");
        float vq[HWn];
        float sq = 0.f;
        const float* rq = bq + lane * HWn;   // lane owns channel t*64+lane
#pragma unroll
        for (int p = 0; p < HWn; ++p) { vq[p] = rq[p]; sq += vq[p]; }
        asm volatile("s_waitcnt lgkmcnt(0)" ::: "memory");  // bq consumed
        if (t < 9) stage_tile(fq_t + (t + 1) * 1600, bq, lane);

        // --- fs phase: wait for fs_t (fq_{t+1} stays in flight)
        if (t < 9) asm volatile("s_waitcnt vmcnt(7)" ::: "memory");
        else       asm volatile("s_waitcnt vmcnt(0)" ::: "memory");
        float vs[HWn];
        float ss = 0.f;
        const float* rs = bs + lane * HWn;
#pragma unroll
        for (int p = 0; p < HWn; ++p) { vs[p] = rs[p]; ss += vs[p]; }
        asm volatile("s_waitcnt lgkmcnt(0)" ::: "memory");  // bs consumed
        if (t < 9) stage_tile(fs_t + (t + 1) * 1600, bs, lane);

        // --- accumulate (overlaps with the 14 outstanding loads)
#pragma unroll
        for (int p = 0; p < HWn; ++p) {
            ms[p] += vs[p] * sq;
            mq[p] += vq[p] * ss;
        }
    }

    // wave-private butterfly reduction: every lane ends with full sums
#pragma unroll
    for (int p = 0; p < HWn; ++p) {
        float a = ms[p], b = mq[p];
#pragma unroll
        for (int d = 1; d < 64; d <<= 1) {
            a += __shfl_xor(a, d);
            b += __shfl_xor(b, d);
        }
        ms[p] = a; mq[p] = b;
    }

    // softmax per 5-wide row, in place (all lanes redundantly; static idx)
    constexpr float inv25 = 1.0f / HWn;
#pragma unroll
    for (int r = 0; r < 5; ++r) {
        {
            float v[5];
#pragma unroll
            for (int j = 0; j < 5; ++j) v[j] = ms[r * 5 + j] * inv25;
            float mx = fmaxf(fmaxf(fmaxf(v[0], v[1]), fmaxf(v[2], v[3])), v[4]);
            float s = 0.f;
#pragma unroll
            for (int j = 0; j < 5; ++j) { v[j] = __expf(v[j] - mx); s += v[j]; }
            const float inv = 1.0f / s;
#pragma unroll
            for (int j = 0; j < 5; ++j) ms[r * 5 + j] = v[j] * inv;
        }
        {
            float v[5];
#pragma unroll
            for (int j = 0; j < 5; ++j) v[j] = mq[r * 5 + j] * inv25;
            float mx = fmaxf(fmaxf(fmaxf(v[0], v[1]), fmaxf(v[2], v[3])), v[4]);
            float s = 0.f;
#pragma unroll
            for (int j = 0; j < 5; ++j) { v[j] = __expf(v[j] - mx); s += v[j]; }
            const float inv = (1.0f / s) * (1.0f / Qn);
#pragma unroll
            for (int j = 0; j < 5; ++j) mq[r * 5 + j] = v[j] * inv;
        }
    }

    if (lane == 0) {
        float* dst = s_att + (size_t)qn * HWn;
#pragma unroll
        for (int j = 0; j < HWn; ++j) dst[j] = ms[j];
    } else if (lane == 32) {
        float* dst = qbar + n * HWn;
#pragma unroll
        for (int j = 0; j < HWn; ++j) atomicAdd(dst + j, mq[j]);
    }
}

// -------------------------------------------------------------------------
// Kernel 2: attended_s[n,c,hw] += (1/Q) * sum_{q in chunk} s_att[q,n,hw]*fs
// grid (16, N, 5): q split into 5 chunks of 40 for occupancy; float4 loads;
// s_att chunk staged in LDS; fp32 atomicAdd into zero-initialized att_s.
// (unchanged this round — per-dispatch counters will attribute its cost)
// -------------------------------------------------------------------------
__global__ __launch_bounds__(256) void agg_kernel(
    const float* __restrict__ fs, const float* __restrict__ s_att,
    float* __restrict__ att_s)
{
    constexpr int QCH = 40;
    __shared__ float w_lds[QCH * HWn];   // 1000 floats
    const int n  = blockIdx.y;
    const int q0 = blockIdx.z * QCH;

    for (int i = threadIdx.x; i < QCH * HWn; i += 256) {
        const int q = q0 + i / HWn;
        const int hw = i % HWn;
        w_lds[i] = s_att[(size_t)(q * Nn + n) * HWn + hw];
    }
    __syncthreads();

    const int f4 = blockIdx.x * 256 + threadIdx.x;   // float4 index, 0..3999
    if (f4 >= CHW / 4) return;
    const int f = f4 * 4;
    const int hw0 = f % HWn, hw1 = (f + 1) % HWn,
              hw2 = (f + 2) % HWn, hw3 = (f + 3) % HWn;

    float4 acc = make_float4(0.f, 0.f, 0.f, 0.f);
#pragma unroll 4
    for (int qi = 0; qi < QCH; ++qi) {
        const int q = q0 + qi;
        const float4 v = *(const float4*)(fs + (size_t)(q * Nn + n) * CHW + f);
        const float* w = &w_lds[qi * HWn];
        acc.x += w[hw0] * v.x;
        acc.y += w[hw1] * v.y;
        acc.z += w[hw2] * v.z;
        acc.w += w[hw3] * v.w;
    }
    float* dst = att_s + (size_t)n * CHW + f;
    atomicAdd(dst + 0, acc.x * (1.0f / Qn));
    atomicAdd(dst + 1, acc.y * (1.0f / Qn));
    atomicAdd(dst + 2, acc.z * (1.0f / Qn));
    atomicAdd(dst + 3, acc.w * (1.0f / Qn));
}

// -------------------------------------------------------------------------
// Kernel 3: out[q,n,c,h] = cos_W(att_s[n,c,h,:], fq[q,n,c,h,:]*qbar[n,h,:]) * 10
// (unchanged this round)
// -------------------------------------------------------------------------
__global__ __launch_bounds__(256) void cos_kernel(
    const float* __restrict__ fq, const float* __restrict__ att_s,
    const float* __restrict__ qbar, float* __restrict__ out)
{
    const size_t idx = (size_t)blockIdx.x * 256 + threadIdx.x;  // over Q*N*C*H
    if (idx >= (size_t)Qn * Nn * Cn * Hn) return;
    const int h = (int)(idx % Hn);
    const size_t t = idx / Hn;
    const int c = (int)(t % Cn);
    const size_t qn = t / Cn;
    const int n = (int)(qn % Nn);

    const float* fqr = fq + (qn * Cn + c) * HWn + h * Wn;
    const float* asr = att_s + ((size_t)n * Cn + c) * HWn + h * Wn;
    const float* qb  = qbar + n * HWn + h * Wn;

    float dot = 0.f, ns2 = 0.f, nq2 = 0.f;
#pragma unroll
    for (int w = 0; w < Wn; ++w) {
        const float aq = fqr[w] * qb[w];
        const float as = asr[w];
        dot += as * aq;
        ns2 += as * as;
        nq2 += aq * aq;
    }
    const float ns = fmaxf(sqrtf(ns2), EPSC);
    const float nq = fmaxf(sqrtf(nq2), EPSC);
    out[idx] = dot / (ns * nq) * TEMP_INV;
}

// -------------------------------------------------------------------------
extern "C" void kernel_launch(void* const* d_in, const int* in_sizes, int n_in,
                              void* d_out, int out_size, void* d_ws, size_t ws_size,
                              hipStream_t stream)
{
    const float* fq = (const float*)d_in[0];   // feature_q [Q,N,C,H,W]
    const float* fs = (const float*)d_in[1];   // feature_s [Q,N,C,H,W]
    float* out = (float*)d_out;                // [Q,N,C,H]

    // Workspace (floats): s_att [Q*N*25] | qbar [25*25 pad->1024] | att_s [N*C*25]
    float* s_att = (float*)d_ws;                          // 125000 floats
    float* qbar  = s_att + (size_t)Qn * Nn * HWn;         // 625 floats (pad 1024)
    float* att_s = qbar + 1024;                           // 400000 floats

    // zero qbar + pad + att_s in one async memset
    hipMemsetAsync(qbar, 0, (1024 + (size_t)Nn * CHW) * sizeof(float), stream);

    attn_kernel<<<Qn * Nn, 64, 0, stream>>>(fq, fs, s_att, qbar);

    dim3 g2((CHW / 4 + 255) / 256, Nn, 5);
    agg_kernel<<<g2, 256, 0, stream>>>(fs, s_att, att_s);

    const size_t total = (size_t)Qn * Nn * Cn * Hn;
    cos_kernel<<<(unsigned)((total + 255) / 256), 256, 0, stream>>>(fq, att_s, qbar, out);
}

// Round 2
// 757.747 us; speedup vs baseline: 1.0174x; 1.0174x over previous
//
#include <hip/hip_runtime.h>

// Problem constants
constexpr int Qn = 200;
constexpr int Nn = 25;
constexpr int Cn = 640;
constexpr int Hn = 5;
constexpr int Wn = 5;
constexpr int HWn = Hn * Wn;            // 25
constexpr int CHW = Cn * HWn;           // 16000
constexpr float TEMP_INV = 10.0f;       // 1 / 0.1
constexpr float EPSC = 1e-8f;

// -------------------------------------------------------------------------
// Kernel 1: one 256-thread WG per (q,n). 5 super-tiles of 128 channels.
// Staging: plain coalesced float4 loads -> regs -> ds_write (NO
// global_load_lds: the LDS-DMA path measured ~5 B/cy/CU = 3.2 TB/s cap,
// structure-invariant across rounds 0/1). LDS 26.6 KB -> 6 WG/CU = 24
// waves/CU; TLP hides latency.
// Consumption: thread t<128 owns fq channel-row t, t>=128 owns fs row
// t-128 (25 floats, stride 25 dwords: odd stride -> max 2-way bank alias,
// free). Row sums exchanged via sums[256] in LDS:
//   ms[p] = sum_c fs[c,p] * sq_c   (accumulated by fs-threads)
//   mq[p] = sum_c fq[c,p] * ss_c   (accumulated by fq-threads)
// Epilogue: wave butterfly + cross-wave LDS combine, row-softmax(ms/25)
// -> s_att ; row-softmax(mq/25)/Q -> atomic into qbar[n].
// -------------------------------------------------------------------------
__global__ __launch_bounds__(256) void attn_kernel(
    const float* __restrict__ fq, const float* __restrict__ fs,
    float* __restrict__ s_att, float* __restrict__ qbar)
{
    __shared__ float buf[6400];    // [fq 128x25 | fs 128x25] floats
    __shared__ float sums[256];    // row sums; reused as red[100]+fm[50]

    const int qn   = blockIdx.x;          // 0 .. Q*N-1
    const int n    = qn % Nn;
    const int tid  = threadIdx.x;
    const int lane = tid & 63;
    const int wave = tid >> 6;

    const float4* fq4 = (const float4*)(fq + (size_t)qn * CHW);
    const float4* fs4 = (const float4*)(fs + (size_t)qn * CHW);

    const bool is_s = (tid >= 128);
    const int rbase = is_s ? 3200 + (tid - 128) * HWn : tid * HWn;

    float acc[HWn];
#pragma unroll
    for (int p = 0; p < HWn; ++p) acc[p] = 0.f;

    for (int t = 0; t < 5; ++t) {
        __syncthreads();           // prev tile's buf+sums fully consumed
        // stage 128 channels of both arrays: 1600 float4s, coalesced
        const int off = t * 800;   // float4 offset within the (q,n) slab
#pragma unroll
        for (int k = 0; k < 6; ++k) {
            const int j = tid + k * 256;                 // 0..1535
            const float4 v = (j < 800) ? fq4[off + j] : fs4[off + j - 800];
            *(float4*)&buf[j * 4] = v;
        }
        if (tid < 64) {
            const int j = tid + 1536;                    // 1536..1599 (fs)
            *(float4*)&buf[j * 4] = fs4[off + j - 800];
        }
        __syncthreads();

        // row read + sum
        const float* row = &buf[rbase];
        float r[HWn];
        float s = 0.f;
#pragma unroll
        for (int p = 0; p < HWn; ++p) { r[p] = row[p]; s += r[p]; }
        sums[tid] = s;
        __syncthreads();

        // partner sum: fq-thread needs ss_c, fs-thread needs sq_c
        const float ps = is_s ? sums[tid - 128] : sums[tid + 128];
#pragma unroll
        for (int p = 0; p < HWn; ++p) acc[p] += r[p] * ps;
    }

    __syncthreads();               // done reading sums; reuse as red/fm

    // wave butterfly: every lane of each wave gets the wave's partial
#pragma unroll
    for (int p = 0; p < HWn; ++p) {
        float a = acc[p];
#pragma unroll
        for (int d = 1; d < 64; d <<= 1) a += __shfl_xor(a, d);
        acc[p] = a;
    }
    // red[wave*25+p]: waves 0,1 = mq partials, waves 2,3 = ms partials
    if (lane == 0) {
#pragma unroll
        for (int p = 0; p < HWn; ++p) sums[wave * HWn + p] = acc[p];
    }
    __syncthreads();
    // fm[0..25) = ms, fm[25..50) = mq   (fm = &sums[100])
    if (tid < 50) {
        float v;
        if (tid < 25) v = sums[50 + tid] + sums[75 + tid];   // ms
        else          v = sums[tid - 25] + sums[tid];        // mq
        sums[100 + tid] = v;
    }
    __syncthreads();

    // 10 rows of 5: rows 0..4 -> s_att (support), rows 5..9 -> q_att -> qbar
    if (tid < 10) {
        const float* fm = &sums[100];
        const int r = tid;
        const float* row = (r < 5) ? &fm[r * 5] : &fm[HWn + (r - 5) * 5];
        float v[5];
        float mx = -1e30f;
#pragma unroll
        for (int j = 0; j < 5; ++j) {
            v[j] = row[j] * (1.0f / HWn);
            mx = fmaxf(mx, v[j]);
        }
        float s = 0.f;
#pragma unroll
        for (int j = 0; j < 5; ++j) { v[j] = __expf(v[j] - mx); s += v[j]; }
        const float inv = 1.0f / s;
        if (r < 5) {
#pragma unroll
            for (int j = 0; j < 5; ++j)
                s_att[(size_t)qn * HWn + r * 5 + j] = v[j] * inv;
        } else {
#pragma unroll
            for (int j = 0; j < 5; ++j)
                atomicAdd(&qbar[n * HWn + (r - 5) * 5 + j],
                          v[j] * inv * (1.0f / Qn));
        }
    }
}

// -------------------------------------------------------------------------
// Kernel 2: attended_s[n,c,hw] += (1/Q) * sum_{q in chunk} s_att[q,n,hw]*fs
// grid (16, N, 5): q split into 5 chunks of 40 for occupancy; float4 loads;
// s_att chunk staged in LDS; fp32 atomicAdd into zero-initialized att_s.
// (unchanged this round — attribution)
// -------------------------------------------------------------------------
__global__ __launch_bounds__(256) void agg_kernel(
    const float* __restrict__ fs, const float* __restrict__ s_att,
    float* __restrict__ att_s)
{
    constexpr int QCH = 40;
    __shared__ float w_lds[QCH * HWn];   // 1000 floats
    const int n  = blockIdx.y;
    const int q0 = blockIdx.z * QCH;

    for (int i = threadIdx.x; i < QCH * HWn; i += 256) {
        const int q = q0 + i / HWn;
        const int hw = i % HWn;
        w_lds[i] = s_att[(size_t)(q * Nn + n) * HWn + hw];
    }
    __syncthreads();

    const int f4 = blockIdx.x * 256 + threadIdx.x;   // float4 index, 0..3999
    if (f4 >= CHW / 4) return;
    const int f = f4 * 4;
    const int hw0 = f % HWn, hw1 = (f + 1) % HWn,
              hw2 = (f + 2) % HWn, hw3 = (f + 3) % HWn;

    float4 acc = make_float4(0.f, 0.f, 0.f, 0.f);
#pragma unroll 4
    for (int qi = 0; qi < QCH; ++qi) {
        const int q = q0 + qi;
        const float4 v = *(const float4*)(fs + (size_t)(q * Nn + n) * CHW + f);
        const float* w = &w_lds[qi * HWn];
        acc.x += w[hw0] * v.x;
        acc.y += w[hw1] * v.y;
        acc.z += w[hw2] * v.z;
        acc.w += w[hw3] * v.w;
    }
    float* dst = att_s + (size_t)n * CHW + f;
    atomicAdd(dst + 0, acc.x * (1.0f / Qn));
    atomicAdd(dst + 1, acc.y * (1.0f / Qn));
    atomicAdd(dst + 2, acc.z * (1.0f / Qn));
    atomicAdd(dst + 3, acc.w * (1.0f / Qn));
}

// -------------------------------------------------------------------------
// Kernel 3: out[q,n,c,h] = cos_W(att_s[n,c,h,:], fq[q,n,c,h,:]*qbar[n,h,:]) * 10
// (unchanged this round)
// -------------------------------------------------------------------------
__global__ __launch_bounds__(256) void cos_kernel(
    const float* __restrict__ fq, const float* __restrict__ att_s,
    const float* __restrict__ qbar, float* __restrict__ out)
{
    const size_t idx = (size_t)blockIdx.x * 256 + threadIdx.x;  // over Q*N*C*H
    if (idx >= (size_t)Qn * Nn * Cn * Hn) return;
    const int h = (int)(idx % Hn);
    const size_t t = idx / Hn;
    const int c = (int)(t % Cn);
    const size_t qn = t / Cn;
    const int n = (int)(qn % Nn);

    const float* fqr = fq + (qn * Cn + c) * HWn + h * Wn;
    const float* asr = att_s + ((size_t)n * Cn + c) * HWn + h * Wn;
    const float* qb  = qbar + n * HWn + h * Wn;

    float dot = 0.f, ns2 = 0.f, nq2 = 0.f;
#pragma unroll
    for (int w = 0; w < Wn; ++w) {
        const float aq = fqr[w] * qb[w];
        const float as = asr[w];
        dot += as * aq;
        ns2 += as * as;
        nq2 += aq * aq;
    }
    const float ns = fmaxf(sqrtf(ns2), EPSC);
    const float nq = fmaxf(sqrtf(nq2), EPSC);
    out[idx] = dot / (ns * nq) * TEMP_INV;
}

// -------------------------------------------------------------------------
extern "C" void kernel_launch(void* const* d_in, const int* in_sizes, int n_in,
                              void* d_out, int out_size, void* d_ws, size_t ws_size,
                              hipStream_t stream)
{
    const float* fq = (const float*)d_in[0];   // feature_q [Q,N,C,H,W]
    const float* fs = (const float*)d_in[1];   // feature_s [Q,N,C,H,W]
    float* out = (float*)d_out;                // [Q,N,C,H]

    // Workspace (floats): s_att [Q*N*25] | qbar [25*25 pad->1024] | att_s [N*C*25]
    float* s_att = (float*)d_ws;                          // 125000 floats
    float* qbar  = s_att + (size_t)Qn * Nn * HWn;         // 625 floats (pad 1024)
    float* att_s = qbar + 1024;                           // 400000 floats

    // zero qbar + pad + att_s in one async memset
    hipMemsetAsync(qbar, 0, (1024 + (size_t)Nn * CHW) * sizeof(float), stream);

    attn_kernel<<<Qn * Nn, 256, 0, stream>>>(fq, fs, s_att, qbar);

    dim3 g2((CHW / 4 + 255) / 256, Nn, 5);
    agg_kernel<<<g2, 256, 0, stream>>>(fs, s_att, att_s);

    const size_t total = (size_t)Qn * Nn * Cn * Hn;
    cos_kernel<<<(unsigned)((total + 255) / 256), 256, 0, stream>>>(fq, att_s, qbar, out);
}

// Round 3
// 752.850 us; speedup vs baseline: 1.0240x; 1.0065x over previous
//
#include <hip/hip_runtime.h>

// Problem constants
constexpr int Qn = 200;
constexpr int Nn = 25;
constexpr int Cn = 640;
constexpr int Hn = 5;
constexpr int Wn = 5;
constexpr int HWn = Hn * Wn;            // 25
constexpr int CHW = Cn * HWn;           // 16000
constexpr float TEMP_INV = 10.0f;       // 1 / 0.1
constexpr float EPSC = 1e-8f;

// -------------------------------------------------------------------------
// Kernel 1: one 256-thread WG per (q,n). 5 super-tiles of 128 channels.
// Plain coalesced float4 staging -> LDS, 24 waves/CU. AT the ~3.3 TB/s
// pure-read ceiling (3 structurally different versions all 190-200 us) —
// do not touch.
// -------------------------------------------------------------------------
__global__ __launch_bounds__(256) void attn_kernel(
    const float* __restrict__ fq, const float* __restrict__ fs,
    float* __restrict__ s_att, float* __restrict__ qbar)
{
    __shared__ float buf[6400];    // [fq 128x25 | fs 128x25] floats
    __shared__ float sums[256];    // row sums; reused as red[100]+fm[50]

    const int qn   = blockIdx.x;          // 0 .. Q*N-1
    const int n    = qn % Nn;
    const int tid  = threadIdx.x;
    const int lane = tid & 63;
    const int wave = tid >> 6;

    const float4* fq4 = (const float4*)(fq + (size_t)qn * CHW);
    const float4* fs4 = (const float4*)(fs + (size_t)qn * CHW);

    const bool is_s = (tid >= 128);
    const int rbase = is_s ? 3200 + (tid - 128) * HWn : tid * HWn;

    float acc[HWn];
#pragma unroll
    for (int p = 0; p < HWn; ++p) acc[p] = 0.f;

    for (int t = 0; t < 5; ++t) {
        __syncthreads();           // prev tile's buf+sums fully consumed
        // stage 128 channels of both arrays: 1600 float4s, coalesced
        const int off = t * 800;   // float4 offset within the (q,n) slab
#pragma unroll
        for (int k = 0; k < 6; ++k) {
            const int j = tid + k * 256;                 // 0..1535
            const float4 v = (j < 800) ? fq4[off + j] : fs4[off + j - 800];
            *(float4*)&buf[j * 4] = v;
        }
        if (tid < 64) {
            const int j = tid + 1536;                    // 1536..1599 (fs)
            *(float4*)&buf[j * 4] = fs4[off + j - 800];
        }
        __syncthreads();

        // row read + sum
        const float* row = &buf[rbase];
        float r[HWn];
        float s = 0.f;
#pragma unroll
        for (int p = 0; p < HWn; ++p) { r[p] = row[p]; s += r[p]; }
        sums[tid] = s;
        __syncthreads();

        // partner sum: fq-thread needs ss_c, fs-thread needs sq_c
        const float ps = is_s ? sums[tid - 128] : sums[tid + 128];
#pragma unroll
        for (int p = 0; p < HWn; ++p) acc[p] += r[p] * ps;
    }

    __syncthreads();               // done reading sums; reuse as red/fm

    // wave butterfly: every lane of each wave gets the wave's partial
#pragma unroll
    for (int p = 0; p < HWn; ++p) {
        float a = acc[p];
#pragma unroll
        for (int d = 1; d < 64; d <<= 1) a += __shfl_xor(a, d);
        acc[p] = a;
    }
    // red[wave*25+p]: waves 0,1 = mq partials, waves 2,3 = ms partials
    if (lane == 0) {
#pragma unroll
        for (int p = 0; p < HWn; ++p) sums[wave * HWn + p] = acc[p];
    }
    __syncthreads();
    // fm[0..25) = ms, fm[25..50) = mq   (fm = &sums[100])
    if (tid < 50) {
        float v;
        if (tid < 25) v = sums[50 + tid] + sums[75 + tid];   // ms
        else          v = sums[tid - 25] + sums[tid];        // mq
        sums[100 + tid] = v;
    }
    __syncthreads();

    // 10 rows of 5: rows 0..4 -> s_att (support), rows 5..9 -> q_att -> qbar
    if (tid < 10) {
        const float* fm = &sums[100];
        const int r = tid;
        const float* row = (r < 5) ? &fm[r * 5] : &fm[HWn + (r - 5) * 5];
        float v[5];
        float mx = -1e30f;
#pragma unroll
        for (int j = 0; j < 5; ++j) {
            v[j] = row[j] * (1.0f / HWn);
            mx = fmaxf(mx, v[j]);
        }
        float s = 0.f;
#pragma unroll
        for (int j = 0; j < 5; ++j) { v[j] = __expf(v[j] - mx); s += v[j]; }
        const float inv = 1.0f / s;
        if (r < 5) {
#pragma unroll
            for (int j = 0; j < 5; ++j)
                s_att[(size_t)qn * HWn + r * 5 + j] = v[j] * inv;
        } else {
#pragma unroll
            for (int j = 0; j < 5; ++j)
                atomicAdd(&qbar[n * HWn + (r - 5) * 5 + j],
                          v[j] * inv * (1.0f / Qn));
        }
    }
}

// -------------------------------------------------------------------------
// Kernel 2 (REWRITTEN, zero atomics): att_s[n, 4j..4j+3] =
//   (1/Q) * sum_{q=0..199} s_att[q,n,hw(.)] * fs[q,n,4j..4j+3]
// grid (64, Nn), 64-thread blocks; thread owns one float4 column j of the
// n-slab, loops over ALL 200 q, plain float4 store at the end. All 200x25
// s_att weights for this n staged in LDS (20 KB). 1600 one-wave blocks =
// ~6 waves/CU; 200-deep unrolled q-loop keeps >>Little's-law bytes in
// flight. Removes 2M global atomicAdds + the att_s zero-init.
// -------------------------------------------------------------------------
__global__ __launch_bounds__(64) void agg_kernel(
    const float* __restrict__ fs, const float* __restrict__ s_att,
    float* __restrict__ att_s)
{
    __shared__ float w_lds[Qn * HWn];    // 5000 floats = 20 KB
    const int n = blockIdx.y;

    // stage s_att[q][n][hw] for all q (reads 20 KB from L2/L3-resident s_att)
    for (int i = threadIdx.x; i < Qn * HWn; i += 64) {
        const int q = i / HWn;
        const int hw = i % HWn;
        w_lds[i] = s_att[(size_t)(q * Nn + n) * HWn + hw];
    }
    __syncthreads();

    const int j = blockIdx.x * 64 + threadIdx.x;     // float4 column, 0..3999
    if (j >= CHW / 4) return;
    const int f = j * 4;
    const int hw0 = f % HWn, hw1 = (f + 1) % HWn,
              hw2 = (f + 2) % HWn, hw3 = (f + 3) % HWn;

    float4 acc = make_float4(0.f, 0.f, 0.f, 0.f);
#pragma unroll 8
    for (int q = 0; q < Qn; ++q) {
        const float4 v = *(const float4*)(fs + (size_t)(q * Nn + n) * CHW + f);
        const float* w = &w_lds[q * HWn];
        acc.x += w[hw0] * v.x;
        acc.y += w[hw1] * v.y;
        acc.z += w[hw2] * v.z;
        acc.w += w[hw3] * v.w;
    }
    float4* dst = (float4*)(att_s + (size_t)n * CHW + f);
    *dst = make_float4(acc.x * (1.0f / Qn), acc.y * (1.0f / Qn),
                       acc.z * (1.0f / Qn), acc.w * (1.0f / Qn));
}

// -------------------------------------------------------------------------
// Kernel 3: out[q,n,c,h] = cos_W(att_s[n,c,h,:], fq[q,n,c,h,:]*qbar[n,h,:]) * 10
// (unchanged this round — attribution)
// -------------------------------------------------------------------------
__global__ __launch_bounds__(256) void cos_kernel(
    const float* __restrict__ fq, const float* __restrict__ att_s,
    const float* __restrict__ qbar, float* __restrict__ out)
{
    const size_t idx = (size_t)blockIdx.x * 256 + threadIdx.x;  // over Q*N*C*H
    if (idx >= (size_t)Qn * Nn * Cn * Hn) return;
    const int h = (int)(idx % Hn);
    const size_t t = idx / Hn;
    const int c = (int)(t % Cn);
    const size_t qn = t / Cn;
    const int n = (int)(qn % Nn);

    const float* fqr = fq + (qn * Cn + c) * HWn + h * Wn;
    const float* asr = att_s + ((size_t)n * Cn + c) * HWn + h * Wn;
    const float* qb  = qbar + n * HWn + h * Wn;

    float dot = 0.f, ns2 = 0.f, nq2 = 0.f;
#pragma unroll
    for (int w = 0; w < Wn; ++w) {
        const float aq = fqr[w] * qb[w];
        const float as = asr[w];
        dot += as * aq;
        ns2 += as * as;
        nq2 += aq * aq;
    }
    const float ns = fmaxf(sqrtf(ns2), EPSC);
    const float nq = fmaxf(sqrtf(nq2), EPSC);
    out[idx] = dot / (ns * nq) * TEMP_INV;
}

// -------------------------------------------------------------------------
extern "C" void kernel_launch(void* const* d_in, const int* in_sizes, int n_in,
                              void* d_out, int out_size, void* d_ws, size_t ws_size,
                              hipStream_t stream)
{
    const float* fq = (const float*)d_in[0];   // feature_q [Q,N,C,H,W]
    const float* fs = (const float*)d_in[1];   // feature_s [Q,N,C,H,W]
    float* out = (float*)d_out;                // [Q,N,C,H]

    // Workspace (floats): s_att [Q*N*25] | qbar [25*25 pad->1024] | att_s [N*C*25]
    float* s_att = (float*)d_ws;                          // 125000 floats
    float* qbar  = s_att + (size_t)Qn * Nn * HWn;         // 625 floats (pad 1024)
    float* att_s = qbar + 1024;                           // 400000 floats

    // zero qbar only (att_s now plain-stored by agg_kernel)
    hipMemsetAsync(qbar, 0, 1024 * sizeof(float), stream);

    attn_kernel<<<Qn * Nn, 256, 0, stream>>>(fq, fs, s_att, qbar);

    dim3 g2((CHW / 4 + 63) / 64, Nn);
    agg_kernel<<<g2, 64, 0, stream>>>(fs, s_att, att_s);

    const size_t total = (size_t)Qn * Nn * Cn * Hn;
    cos_kernel<<<(unsigned)((total + 255) / 256), 256, 0, stream>>>(fq, att_s, qbar, out);
}